// Round 1
// 446.438 us; speedup vs baseline: 1.1240x; 1.1240x over previous
//
#include <hip/hip_runtime.h>

// BezierAlign, R3: NCHW->NHWC transpose, then channel-major gather with
//  (a) per-pixel corner DEDUP: the 4 subsamples' 16 bilinear corners are
//      merged (static O(16^2) register merge, zero-weight corners dropped,
//      padded to x4) -> ~2.5x fewer 1KB gather requests into L2/L3.
//  (b) nontemporal output stores: 268MB output stream no longer evicts the
//      52MB NHWC feat from L3 -> HBM FETCH collapses.
//  (c) XCD-aware block swizzle: all 16 ph-blocks of one ROI land on one XCD
//      (blk%8 -> XCD), sharing overlapping y-bands in that XCD's 4MB L2.

#define OUT_H 16
#define OUT_W 64
#define SPATIAL_SCALE 0.25f
#define C_DIM 256
#define H_DIM 160
#define W_DIM 160
#define HW_DIM (H_DIM * W_DIM)

// ---------- Pass 1: NCHW -> NHWC (per batch: transpose 256 x 25600) ----------
__global__ __launch_bounds__(256) void nchw_to_nhwc(const float* __restrict__ in,
                                                    float* __restrict__ outb) {
  __shared__ float lds[64][65];
  const int b = blockIdx.x;
  const int n = b / 1600;          // 1600 tiles per batch: 4 (c) x 400 (hw)
  const int t = b - n * 1600;
  const int tc = t & 3;
  const int tp = t >> 2;
  const int c0 = tc * 64, p0 = tp * 64;
  const float* A = in + (size_t)n * C_DIM * HW_DIM;
  float* B = outb + (size_t)n * HW_DIM * C_DIM;
  const int j = threadIdx.x & 63;
  const int i0 = threadIdx.x >> 6;
#pragma unroll
  for (int k = 0; k < 16; ++k) {
    const int i = i0 + 4 * k;
    lds[i][j] = A[(size_t)(c0 + i) * HW_DIM + (p0 + j)];   // coalesced along hw
  }
  __syncthreads();
#pragma unroll
  for (int k = 0; k < 16; ++k) {
    const int jj = i0 + 4 * k;
    B[(size_t)(p0 + jj) * C_DIM + (c0 + j)] = lds[j][jj];  // coalesced along c
  }
}

// ---------- Pass 2: gather from NHWC ----------
__global__ __launch_bounds__(256) void bezier_gather(const float* __restrict__ feat,
                                                     const float* __restrict__ rois,
                                                     float* __restrict__ out) {
  __shared__ int2 s_geo[OUT_W * 16];     // deduped {pos, weight-bits} per pw
  __shared__ int s_cnt[OUT_W];           // entries per pw (multiple of 4)
  __shared__ float s_tile[64][65];       // store-transpose tile (c_loc x pw)

  // XCD swizzle: HW round-robins blocks over 8 XCDs by blockIdx%8; remap so
  // each XCD owns a contiguous chunk of (r,ph) work -> 16 ph-blocks of one r
  // are co-resident on one XCD (overlapping y-bands hit its L2).
  const int nblk = (int)gridDim.x;       // R*16, always divisible by 8
  const int chunk = nblk >> 3;
  const int b0 = (int)blockIdx.x;
  const int wk = (b0 & 7) * chunk + (b0 >> 3);
  const int r = wk >> 4;
  const int ph = wk & 15;

  const int tid = threadIdx.x;
  const int lane = tid & 63;
  const int q = tid >> 6;                // wave id = pw quarter

  const float* roi = rois + (size_t)r * 17;
  const int n = (int)roi[0];

  if (tid < 64) {
    const int pw = tid;
    float px[8], py[8];
#pragma unroll
    for (int k = 0; k < 8; ++k) {
      px[k] = roi[1 + 2 * k] * SPATIAL_SCALE;
      py[k] = roi[2 + 2 * k] * SPATIAL_SCALE;
    }
    const float u = (float)pw * (1.0f / OUT_W);
    const float vv = (float)ph * (1.0f / OUT_H);
    const float mt = 1.0f - u;
    const float b0f = mt * mt * mt;
    const float b1f = 3.0f * u * mt * mt;
    const float b2f = 3.0f * u * u * mt;
    const float b3f = u * u * u;
    const float x0 = b0f * px[0] + b1f * px[1] + b2f * px[2] + b3f * px[3];
    const float y0 = b0f * py[0] + b1f * py[1] + b2f * py[2] + b3f * py[3];
    const float x1 = b0f * px[4] + b1f * px[5] + b2f * px[6] + b3f * px[7];
    const float y1 = b0f * py[4] + b1f * py[5] + b2f * py[6] + b3f * py[7];
    const float xc = x1 * vv + x0 * (1.0f - vv) - 0.5f;
    const float yc = y1 * vv + y0 * (1.0f - vv) - 0.5f;
    const float roi_w = fmaxf(fabsf(px[0] - px[3]), fabsf(px[4] - px[7]));
    const float roi_h = fmaxf(fabsf(py[0] - py[3]), fabsf(py[4] - py[7]));
    const float bin_h = roi_h * (1.0f / OUT_H);
    const float bin_w = roi_w * (1.0f / OUT_W);

    int posv[16];
    float wv[16];
#pragma unroll
    for (int s = 0; s < 4; ++s) {
      const int iy = s >> 1, ix = s & 1;
      float y = yc - 0.5f * bin_h + ((float)iy + 0.5f) * bin_h * 0.5f;
      float x = xc - 0.5f * bin_w + ((float)ix + 0.5f) * bin_w * 0.5f;
      const bool valid = (y > -1.0f) && (y < (float)H_DIM) &&
                         (x > -1.0f) && (x < (float)W_DIM);
      y = fmaxf(y, 0.0f);
      x = fmaxf(x, 0.0f);
      int yl = min((int)y, H_DIM - 1);
      int xl = min((int)x, W_DIM - 1);
      const int yh = min(yl + 1, H_DIM - 1);
      const int xh = min(xl + 1, W_DIM - 1);
      if (yl >= H_DIM - 1) y = (float)yl;
      if (xl >= W_DIM - 1) x = (float)xl;
      const float ly = y - (float)yl;
      const float lx = x - (float)xl;
      const float hy = 1.0f - ly;
      const float hx = 1.0f - lx;
      const float vw = valid ? 0.25f : 0.0f;
      posv[4 * s + 0] = yl * W_DIM + xl;  wv[4 * s + 0] = vw * hy * hx;
      posv[4 * s + 1] = yl * W_DIM + xh;  wv[4 * s + 1] = vw * hy * lx;
      posv[4 * s + 2] = yh * W_DIM + xl;  wv[4 * s + 2] = vw * ly * hx;
      posv[4 * s + 3] = yh * W_DIM + xh;  wv[4 * s + 3] = vw * ly * lx;
    }
    // Static O(16^2) merge of duplicate positions (all indices compile-time
    // constant -> stays in registers, no scratch).
#pragma unroll
    for (int i = 0; i < 16; ++i) {
#pragma unroll
      for (int jj = i + 1; jj < 16; ++jj) {
        if (posv[i] == posv[jj]) { wv[i] += wv[jj]; wv[jj] = 0.0f; }
      }
    }
    // Compact nonzero-weight entries into LDS; pad count to multiple of 4
    // with zero-weight clones of entry 0 (safe address, adds 0).
    int cnt = 0;
    int first_pos = 0;
#pragma unroll
    for (int i = 0; i < 16; ++i) {
      if (wv[i] != 0.0f) {
        if (cnt == 0) first_pos = posv[i];
        s_geo[pw * 16 + cnt] = make_int2(posv[i], __float_as_int(wv[i]));
        ++cnt;
      }
    }
    while (cnt & 3) {
      s_geo[pw * 16 + cnt] = make_int2(first_pos, 0);
      ++cnt;
    }
    s_cnt[pw] = cnt;
  }
  __syncthreads();

  const float* fb = feat + (size_t)n * ((size_t)HW_DIM * C_DIM);
  const int voff = lane * 4;             // this thread's 4-channel base (floats)
  const int pw0 = q * 16;

  float4 acc[16];
#pragma unroll
  for (int j = 0; j < 16; ++j) acc[j] = make_float4(0.f, 0.f, 0.f, 0.f);

#pragma unroll
  for (int j = 0; j < 16; ++j) {
    const int cnt = __builtin_amdgcn_readfirstlane(s_cnt[pw0 + j]);
    const int2* gp = s_geo + (pw0 + j) * 16;
    float4 a = acc[j];
    for (int k = 0; k < cnt; k += 4) {
      const int2 g0 = gp[k + 0];
      const int2 g1 = gp[k + 1];
      const int2 g2 = gp[k + 2];
      const int2 g3 = gp[k + 3];
      const int p0i = __builtin_amdgcn_readfirstlane(g0.x);
      const int p1i = __builtin_amdgcn_readfirstlane(g1.x);
      const int p2i = __builtin_amdgcn_readfirstlane(g2.x);
      const int p3i = __builtin_amdgcn_readfirstlane(g3.x);
      const float w0 = __int_as_float(__builtin_amdgcn_readfirstlane(g0.y));
      const float w1 = __int_as_float(__builtin_amdgcn_readfirstlane(g1.y));
      const float w2 = __int_as_float(__builtin_amdgcn_readfirstlane(g2.y));
      const float w3 = __int_as_float(__builtin_amdgcn_readfirstlane(g3.y));
      const float4 v0 = *(const float4*)(fb + (size_t)p0i * C_DIM + voff);
      const float4 v1 = *(const float4*)(fb + (size_t)p1i * C_DIM + voff);
      const float4 v2 = *(const float4*)(fb + (size_t)p2i * C_DIM + voff);
      const float4 v3 = *(const float4*)(fb + (size_t)p3i * C_DIM + voff);
      a.x = fmaf(w0, v0.x, a.x); a.y = fmaf(w0, v0.y, a.y);
      a.z = fmaf(w0, v0.z, a.z); a.w = fmaf(w0, v0.w, a.w);
      a.x = fmaf(w1, v1.x, a.x); a.y = fmaf(w1, v1.y, a.y);
      a.z = fmaf(w1, v1.z, a.z); a.w = fmaf(w1, v1.w, a.w);
      a.x = fmaf(w2, v2.x, a.x); a.y = fmaf(w2, v2.y, a.y);
      a.z = fmaf(w2, v2.z, a.z); a.w = fmaf(w2, v2.w, a.w);
      a.x = fmaf(w3, v3.x, a.x); a.y = fmaf(w3, v3.y, a.y);
      a.z = fmaf(w3, v3.z, a.z); a.w = fmaf(w3, v3.w, a.w);
    }
    acc[j] = a;
  }

  // Store: 4 rounds of 64 channels, LDS-transposed for pw-contiguous stores.
  // Nontemporal: output is write-once streaming; keep it out of L2/L3 so the
  // 52MB NHWC feat stays resident across the whole dispatch (and iterations).
  const int cg = lane >> 4;              // which 64-ch group this thread holds
  const int clb = (lane & 15) * 4;       // c offset within that group
#pragma unroll 1
  for (int g = 0; g < 4; ++g) {
    __syncthreads();
    if (cg == g) {
#pragma unroll
      for (int j = 0; j < 16; ++j) {
        s_tile[clb + 0][pw0 + j] = acc[j].x;
        s_tile[clb + 1][pw0 + j] = acc[j].y;
        s_tile[clb + 2][pw0 + j] = acc[j].z;
        s_tile[clb + 3][pw0 + j] = acc[j].w;
      }
    }
    __syncthreads();
    float* ob = out + (((size_t)r * C_DIM + g * 64) * OUT_H + ph) * OUT_W;
#pragma unroll
    for (int kk = 0; kk < 16; ++kk) {
      const int cl = q + 4 * kk;
      __builtin_nontemporal_store(s_tile[cl][lane],
                                  ob + (size_t)cl * (OUT_H * OUT_W) + lane);
    }
  }
}

// ---------- Fallback (R1 kernel) if workspace too small for NHWC copy ----------
__global__ __launch_bounds__(256) void bezier_align_fallback(
    const float* __restrict__ input, const float* __restrict__ rois,
    float* __restrict__ out) {
  const int blk = blockIdx.x;
  const int r = blk >> 4;
  const int ph = blk & 15;
  const int lane = threadIdx.x & 63;
  const int wave = threadIdx.x >> 6;
  const int pw = lane;
  const float* roi = rois + (size_t)r * 17;
  const int n = (int)roi[0];
  float px[8], py[8];
#pragma unroll
  for (int k = 0; k < 8; ++k) {
    px[k] = roi[1 + 2 * k] * SPATIAL_SCALE;
    py[k] = roi[2 + 2 * k] * SPATIAL_SCALE;
  }
  const float u = (float)pw * (1.0f / OUT_W);
  const float vv = (float)ph * (1.0f / OUT_H);
  const float mt = 1.0f - u;
  const float b0 = mt * mt * mt;
  const float b1 = 3.0f * u * mt * mt;
  const float b2 = 3.0f * u * u * mt;
  const float b3 = u * u * u;
  const float x0 = b0 * px[0] + b1 * px[1] + b2 * px[2] + b3 * px[3];
  const float y0 = b0 * py[0] + b1 * py[1] + b2 * py[2] + b3 * py[3];
  const float x1 = b0 * px[4] + b1 * px[5] + b2 * px[6] + b3 * px[7];
  const float y1 = b0 * py[4] + b1 * py[5] + b2 * py[6] + b3 * py[7];
  const float xc = x1 * vv + x0 * (1.0f - vv) - 0.5f;
  const float yc = y1 * vv + y0 * (1.0f - vv) - 0.5f;
  const float roi_w = fmaxf(fabsf(px[0] - px[3]), fabsf(px[4] - px[7]));
  const float roi_h = fmaxf(fabsf(py[0] - py[3]), fabsf(py[4] - py[7]));
  const float bin_h = roi_h * (1.0f / OUT_H);
  const float bin_w = roi_w * (1.0f / OUT_W);
  int off[16];
  float wgt[16];
#pragma unroll
  for (int s = 0; s < 4; ++s) {
    const int iy = s >> 1, ix = s & 1;
    float y = yc - 0.5f * bin_h + ((float)iy + 0.5f) * bin_h * 0.5f;
    float x = xc - 0.5f * bin_w + ((float)ix + 0.5f) * bin_w * 0.5f;
    const bool valid = (y > -1.0f) && (y < (float)H_DIM) &&
                       (x > -1.0f) && (x < (float)W_DIM);
    y = fmaxf(y, 0.0f);
    x = fmaxf(x, 0.0f);
    int yl = min((int)y, H_DIM - 1);
    int xl = min((int)x, W_DIM - 1);
    const int yh = min(yl + 1, H_DIM - 1);
    const int xh = min(xl + 1, W_DIM - 1);
    if (yl >= H_DIM - 1) y = (float)yl;
    if (xl >= W_DIM - 1) x = (float)xl;
    const float ly = y - (float)yl;
    const float lx = x - (float)xl;
    const float hy = 1.0f - ly;
    const float hx = 1.0f - lx;
    const float vw = valid ? 0.25f : 0.0f;
    wgt[4 * s + 0] = vw * hy * hx;  off[4 * s + 0] = yl * W_DIM + xl;
    wgt[4 * s + 1] = vw * hy * lx;  off[4 * s + 1] = yl * W_DIM + xh;
    wgt[4 * s + 2] = vw * ly * hx;  off[4 * s + 2] = yh * W_DIM + xl;
    wgt[4 * s + 3] = vw * ly * lx;  off[4 * s + 3] = yh * W_DIM + xh;
  }
  const size_t HW = (size_t)HW_DIM;
  const float* base = input + (size_t)n * C_DIM * HW;
  float* outp = out + (((size_t)r * C_DIM) * OUT_H + ph) * OUT_W + pw;
  const int c0 = wave * 64;
#pragma unroll 2
  for (int cc = 0; cc < 64; ++cc) {
    const int c = c0 + cc;
    const float* p = base + (size_t)c * HW;
    float acc = 0.0f;
#pragma unroll
    for (int k = 0; k < 16; ++k) acc = fmaf(wgt[k], p[off[k]], acc);
    outp[(size_t)c * (OUT_H * OUT_W)] = acc;
  }
}

extern "C" void kernel_launch(void* const* d_in, const int* in_sizes, int n_in,
                              void* d_out, int out_size, void* d_ws, size_t ws_size,
                              hipStream_t stream) {
  const float* input = (const float*)d_in[0];
  const float* rois = (const float*)d_in[1];
  float* out = (float*)d_out;
  const int R = in_sizes[1] / 17;
  const int N = in_sizes[0] / (C_DIM * HW_DIM);
  const size_t need = (size_t)in_sizes[0] * sizeof(float);
  if (ws_size >= need) {
    float* nhwc = (float*)d_ws;
    nchw_to_nhwc<<<dim3(N * 1600), dim3(256), 0, stream>>>(input, nhwc);
    bezier_gather<<<dim3(R * OUT_H), dim3(256), 0, stream>>>(nhwc, rois, out);
  } else {
    bezier_align_fallback<<<dim3(R * OUT_H), dim3(256), 0, stream>>>(input, rois, out);
  }
}

// Round 5
// 431.346 us; speedup vs baseline: 1.1633x; 1.0350x over previous
//
#include <hip/hip_runtime.h>

// BezierAlign, R7 (= R4 + fixes: inline fns for .w macro hygiene, clang
// ext_vector for nontemporal vector load):
//  (a) transpose pass vectorized: float4 global loads + b128 LDS reads
//      (2-way-conflict-free 64x65 tile), float4 global stores.
//  (b) gather: per-pw deduped corner list, ALL cnt loads (4..16) issued
//      before the first FMA via wave-uniform predicated groups -> MLP 4->~9.
//  (c) nontemporal output stores + nontemporal NCHW input loads keep the
//      52MB NHWC feat resident in L3; XCD-aware block swizzle for L2.

#define OUT_H 16
#define OUT_W 64
#define SPATIAL_SCALE 0.25f
#define C_DIM 256
#define H_DIM 160
#define W_DIM 160
#define HW_DIM (H_DIM * W_DIM)

typedef __attribute__((ext_vector_type(4))) float fvec4;  // native clang vec

// ---------- Pass 1: NCHW -> NHWC (vectorized transpose) ----------
__global__ __launch_bounds__(256) void nchw_to_nhwc(const float* __restrict__ in,
                                                    float* __restrict__ outb) {
  __shared__ float t[64][65];            // t[hw_local][c_local]
  const int b = blockIdx.x;
  const int n = b / 1600;                // 1600 tiles per batch: 4 (c) x 400 (hw)
  const int tile = b - n * 1600;
  const int tc = tile & 3;
  const int tp = tile >> 2;
  const int c0 = tc * 64, p0 = tp * 64;
  const float* A = in + (size_t)n * C_DIM * HW_DIM;
  float* B = outb + (size_t)n * HW_DIM * C_DIM;
  const int q = threadIdx.x & 15;        // float4 column index
  const int row = threadIdx.x >> 4;      // 16 rows per pass
#pragma unroll
  for (int k = 0; k < 4; ++k) {
    const int c = row + 16 * k;
    const fvec4 v = __builtin_nontemporal_load(
        (const fvec4*)(A + (size_t)(c0 + c) * HW_DIM + p0 + 4 * q));
    t[4 * q + 0][c] = v[0];              // scalar scatter: 2-way conflict (free)
    t[4 * q + 1][c] = v[1];
    t[4 * q + 2][c] = v[2];
    t[4 * q + 3][c] = v[3];
  }
  __syncthreads();
#pragma unroll
  for (int k = 0; k < 4; ++k) {
    const int h = row + 16 * k;
    fvec4 v;                             // contiguous b128 read along c
    v[0] = t[h][4 * q + 0];
    v[1] = t[h][4 * q + 1];
    v[2] = t[h][4 * q + 2];
    v[3] = t[h][4 * q + 3];
    *(fvec4*)(B + (size_t)(p0 + h) * C_DIM + c0 + 4 * q) = v;
  }
}

// -- helpers (functions, not macros: avoid token-substitution on .w members) --
__device__ __forceinline__ float4 ldv(const float* __restrict__ fb, int pos,
                                      int voff) {
  const int p = __builtin_amdgcn_readfirstlane(pos);   // wave-uniform -> SGPR
  return *(const float4*)(fb + (size_t)p * C_DIM + voff);
}
__device__ __forceinline__ float wgt(int wb) {
  return __int_as_float(__builtin_amdgcn_readfirstlane(wb));
}
__device__ __forceinline__ void fma4(float4& a, float s, const float4& b) {
  a.x = fmaf(s, b.x, a.x);
  a.y = fmaf(s, b.y, a.y);
  a.z = fmaf(s, b.z, a.z);
  a.w = fmaf(s, b.w, a.w);
}

// ---------- Pass 2: gather from NHWC ----------
__global__ __launch_bounds__(256) void bezier_gather(const float* __restrict__ feat,
                                                     const float* __restrict__ rois,
                                                     float* __restrict__ out) {
  __shared__ int2 s_geo[OUT_W * 16];     // deduped {pos, weight-bits} per pw
  __shared__ int s_cnt[OUT_W];           // entries per pw (multiple of 4)
  __shared__ float s_tile[64][65];       // store-transpose tile (c_loc x pw)

  // XCD swizzle: blk%8 -> XCD; remap so each XCD owns a contiguous chunk of
  // (r,ph) work (overlapping y-bands share that XCD's 4MB L2).
  const int nblk = (int)gridDim.x;       // R*16, divisible by 8
  const int chunk = nblk >> 3;
  const int b0 = (int)blockIdx.x;
  const int wk = (b0 & 7) * chunk + (b0 >> 3);
  const int r = wk >> 4;
  const int ph = wk & 15;

  const int tid = threadIdx.x;
  const int lane = tid & 63;
  const int q = tid >> 6;                // wave id = pw quarter

  const float* roi = rois + (size_t)r * 17;
  const int n = (int)roi[0];

  if (tid < 64) {
    const int pw = tid;
    float px[8], py[8];
#pragma unroll
    for (int k = 0; k < 8; ++k) {
      px[k] = roi[1 + 2 * k] * SPATIAL_SCALE;
      py[k] = roi[2 + 2 * k] * SPATIAL_SCALE;
    }
    const float u = (float)pw * (1.0f / OUT_W);
    const float vv = (float)ph * (1.0f / OUT_H);
    const float mt = 1.0f - u;
    const float b0f = mt * mt * mt;
    const float b1f = 3.0f * u * mt * mt;
    const float b2f = 3.0f * u * u * mt;
    const float b3f = u * u * u;
    const float x0 = b0f * px[0] + b1f * px[1] + b2f * px[2] + b3f * px[3];
    const float y0 = b0f * py[0] + b1f * py[1] + b2f * py[2] + b3f * py[3];
    const float x1 = b0f * px[4] + b1f * px[5] + b2f * px[6] + b3f * px[7];
    const float y1 = b0f * py[4] + b1f * py[5] + b2f * py[6] + b3f * py[7];
    const float xc = x1 * vv + x0 * (1.0f - vv) - 0.5f;
    const float yc = y1 * vv + y0 * (1.0f - vv) - 0.5f;
    const float roi_w = fmaxf(fabsf(px[0] - px[3]), fabsf(px[4] - px[7]));
    const float roi_h = fmaxf(fabsf(py[0] - py[3]), fabsf(py[4] - py[7]));
    const float bin_h = roi_h * (1.0f / OUT_H);
    const float bin_w = roi_w * (1.0f / OUT_W);

    int posv[16];
    float wv[16];
#pragma unroll
    for (int s = 0; s < 4; ++s) {
      const int iy = s >> 1, ix = s & 1;
      float y = yc - 0.5f * bin_h + ((float)iy + 0.5f) * bin_h * 0.5f;
      float x = xc - 0.5f * bin_w + ((float)ix + 0.5f) * bin_w * 0.5f;
      const bool valid = (y > -1.0f) && (y < (float)H_DIM) &&
                         (x > -1.0f) && (x < (float)W_DIM);
      y = fmaxf(y, 0.0f);
      x = fmaxf(x, 0.0f);
      int yl = min((int)y, H_DIM - 1);
      int xl = min((int)x, W_DIM - 1);
      const int yh = min(yl + 1, H_DIM - 1);
      const int xh = min(xl + 1, W_DIM - 1);
      if (yl >= H_DIM - 1) y = (float)yl;
      if (xl >= W_DIM - 1) x = (float)xl;
      const float ly = y - (float)yl;
      const float lx = x - (float)xl;
      const float hy = 1.0f - ly;
      const float hx = 1.0f - lx;
      const float vw = valid ? 0.25f : 0.0f;
      posv[4 * s + 0] = yl * W_DIM + xl;  wv[4 * s + 0] = vw * hy * hx;
      posv[4 * s + 1] = yl * W_DIM + xh;  wv[4 * s + 1] = vw * hy * lx;
      posv[4 * s + 2] = yh * W_DIM + xl;  wv[4 * s + 2] = vw * ly * hx;
      posv[4 * s + 3] = yh * W_DIM + xh;  wv[4 * s + 3] = vw * ly * lx;
    }
    // Static O(16^2) register merge of duplicate positions.
#pragma unroll
    for (int i = 0; i < 16; ++i) {
#pragma unroll
      for (int jj = i + 1; jj < 16; ++jj) {
        if (posv[i] == posv[jj]) { wv[i] += wv[jj]; wv[jj] = 0.0f; }
      }
    }
    // Compact nonzero entries; pad to multiple of 4 with zero-weight clones.
    int cnt = 0;
    int first_pos = 0;
#pragma unroll
    for (int i = 0; i < 16; ++i) {
      if (wv[i] != 0.0f) {
        if (cnt == 0) first_pos = posv[i];
        s_geo[pw * 16 + cnt] = make_int2(posv[i], __float_as_int(wv[i]));
        ++cnt;
      }
    }
    while (cnt & 3) {
      s_geo[pw * 16 + cnt] = make_int2(first_pos, 0);
      ++cnt;
    }
    s_cnt[pw] = cnt;
  }
  __syncthreads();

  const float* fb = feat + (size_t)n * ((size_t)HW_DIM * C_DIM);
  const int voff = lane * 4;             // this thread's 4-channel base (floats)
  const int pw0 = q * 16;

  float4 acc[16];
#pragma unroll
  for (int j = 0; j < 16; ++j) acc[j] = make_float4(0.f, 0.f, 0.f, 0.f);

  const float4 fz = make_float4(0.f, 0.f, 0.f, 0.f);
  const int4 iz = make_int4(0, 0, 0, 0);

#pragma unroll
  for (int j = 0; j < 16; ++j) {
    const int cnt = __builtin_amdgcn_readfirstlane(s_cnt[pw0 + j]);
    const int4* gp4 = (const int4*)(s_geo + (pw0 + j) * 16);  // 2 entries/int4
    float4 a = acc[j];
    int4 e0, e1, e2 = iz, e3 = iz, e4 = iz, e5 = iz, e6 = iz, e7 = iz;
    float4 v0, v1, v2, v3, v4 = fz, v5 = fz, v6 = fz, v7 = fz,
           v8 = fz, v9 = fz, v10 = fz, v11 = fz,
           v12 = fz, v13 = fz, v14 = fz, v15 = fz;
    // Issue ALL gathers before any FMA (wave-uniform scalar branches).
    e0 = gp4[0]; e1 = gp4[1];
    v0 = ldv(fb, e0.x, voff); v1 = ldv(fb, e0.z, voff);
    v2 = ldv(fb, e1.x, voff); v3 = ldv(fb, e1.z, voff);
    if (cnt > 4) {
      e2 = gp4[2]; e3 = gp4[3];
      v4 = ldv(fb, e2.x, voff); v5 = ldv(fb, e2.z, voff);
      v6 = ldv(fb, e3.x, voff); v7 = ldv(fb, e3.z, voff);
    }
    if (cnt > 8) {
      e4 = gp4[4]; e5 = gp4[5];
      v8 = ldv(fb, e4.x, voff); v9 = ldv(fb, e4.z, voff);
      v10 = ldv(fb, e5.x, voff); v11 = ldv(fb, e5.z, voff);
    }
    if (cnt > 12) {
      e6 = gp4[6]; e7 = gp4[7];
      v12 = ldv(fb, e6.x, voff); v13 = ldv(fb, e6.z, voff);
      v14 = ldv(fb, e7.x, voff); v15 = ldv(fb, e7.z, voff);
    }
    // Accumulate.
    fma4(a, wgt(e0.y), v0); fma4(a, wgt(e0.w), v1);
    fma4(a, wgt(e1.y), v2); fma4(a, wgt(e1.w), v3);
    if (cnt > 4) {
      fma4(a, wgt(e2.y), v4); fma4(a, wgt(e2.w), v5);
      fma4(a, wgt(e3.y), v6); fma4(a, wgt(e3.w), v7);
    }
    if (cnt > 8) {
      fma4(a, wgt(e4.y), v8); fma4(a, wgt(e4.w), v9);
      fma4(a, wgt(e5.y), v10); fma4(a, wgt(e5.w), v11);
    }
    if (cnt > 12) {
      fma4(a, wgt(e6.y), v12); fma4(a, wgt(e6.w), v13);
      fma4(a, wgt(e7.y), v14); fma4(a, wgt(e7.w), v15);
    }
    acc[j] = a;
  }

  // Store: 4 rounds of 64 channels, LDS-transposed for pw-contiguous stores.
  // Nontemporal: keep the 268MB output stream out of L2/L3.
  const int cg = lane >> 4;              // which 64-ch group this thread holds
  const int clb = (lane & 15) * 4;       // c offset within that group
#pragma unroll 1
  for (int g = 0; g < 4; ++g) {
    __syncthreads();
    if (cg == g) {
#pragma unroll
      for (int j = 0; j < 16; ++j) {
        s_tile[clb + 0][pw0 + j] = acc[j].x;
        s_tile[clb + 1][pw0 + j] = acc[j].y;
        s_tile[clb + 2][pw0 + j] = acc[j].z;
        s_tile[clb + 3][pw0 + j] = acc[j].w;
      }
    }
    __syncthreads();
    float* ob = out + (((size_t)r * C_DIM + g * 64) * OUT_H + ph) * OUT_W;
#pragma unroll
    for (int kk = 0; kk < 16; ++kk) {
      const int cl = q + 4 * kk;
      __builtin_nontemporal_store(s_tile[cl][lane],
                                  ob + (size_t)cl * (OUT_H * OUT_W) + lane);
    }
  }
}

// ---------- Fallback (R1 kernel) if workspace too small for NHWC copy ----------
__global__ __launch_bounds__(256) void bezier_align_fallback(
    const float* __restrict__ input, const float* __restrict__ rois,
    float* __restrict__ out) {
  const int blk = blockIdx.x;
  const int r = blk >> 4;
  const int ph = blk & 15;
  const int lane = threadIdx.x & 63;
  const int wave = threadIdx.x >> 6;
  const int pw = lane;
  const float* roi = rois + (size_t)r * 17;
  const int n = (int)roi[0];
  float px[8], py[8];
#pragma unroll
  for (int k = 0; k < 8; ++k) {
    px[k] = roi[1 + 2 * k] * SPATIAL_SCALE;
    py[k] = roi[2 + 2 * k] * SPATIAL_SCALE;
  }
  const float u = (float)pw * (1.0f / OUT_W);
  const float vv = (float)ph * (1.0f / OUT_H);
  const float mt = 1.0f - u;
  const float b0 = mt * mt * mt;
  const float b1 = 3.0f * u * mt * mt;
  const float b2 = 3.0f * u * u * mt;
  const float b3 = u * u * u;
  const float x0 = b0 * px[0] + b1 * px[1] + b2 * px[2] + b3 * px[3];
  const float y0 = b0 * py[0] + b1 * py[1] + b2 * py[2] + b3 * py[3];
  const float x1 = b0 * px[4] + b1 * px[5] + b2 * px[6] + b3 * px[7];
  const float y1 = b0 * py[4] + b1 * py[5] + b2 * py[6] + b3 * py[7];
  const float xc = x1 * vv + x0 * (1.0f - vv) - 0.5f;
  const float yc = y1 * vv + y0 * (1.0f - vv) - 0.5f;
  const float roi_w = fmaxf(fabsf(px[0] - px[3]), fabsf(px[4] - px[7]));
  const float roi_h = fmaxf(fabsf(py[0] - py[3]), fabsf(py[4] - py[7]));
  const float bin_h = roi_h * (1.0f / OUT_H);
  const float bin_w = roi_w * (1.0f / OUT_W);
  int off[16];
  float wgt_[16];
#pragma unroll
  for (int s = 0; s < 4; ++s) {
    const int iy = s >> 1, ix = s & 1;
    float y = yc - 0.5f * bin_h + ((float)iy + 0.5f) * bin_h * 0.5f;
    float x = xc - 0.5f * bin_w + ((float)ix + 0.5f) * bin_w * 0.5f;
    const bool valid = (y > -1.0f) && (y < (float)H_DIM) &&
                       (x > -1.0f) && (x < (float)W_DIM);
    y = fmaxf(y, 0.0f);
    x = fmaxf(x, 0.0f);
    int yl = min((int)y, H_DIM - 1);
    int xl = min((int)x, W_DIM - 1);
    const int yh = min(yl + 1, H_DIM - 1);
    const int xh = min(xl + 1, W_DIM - 1);
    if (yl >= H_DIM - 1) y = (float)yl;
    if (xl >= W_DIM - 1) x = (float)xl;
    const float ly = y - (float)yl;
    const float lx = x - (float)xl;
    const float hy = 1.0f - ly;
    const float hx = 1.0f - lx;
    const float vw = valid ? 0.25f : 0.0f;
    wgt_[4 * s + 0] = vw * hy * hx;  off[4 * s + 0] = yl * W_DIM + xl;
    wgt_[4 * s + 1] = vw * hy * lx;  off[4 * s + 1] = yl * W_DIM + xh;
    wgt_[4 * s + 2] = vw * ly * hx;  off[4 * s + 2] = yh * W_DIM + xl;
    wgt_[4 * s + 3] = vw * ly * lx;  off[4 * s + 3] = yh * W_DIM + xh;
  }
  const size_t HW = (size_t)HW_DIM;
  const float* base = input + (size_t)n * C_DIM * HW;
  float* outp = out + (((size_t)r * C_DIM) * OUT_H + ph) * OUT_W + pw;
  const int c0 = wave * 64;
#pragma unroll 2
  for (int cc = 0; cc < 64; ++cc) {
    const int c = c0 + cc;
    const float* p = base + (size_t)c * HW;
    float acc = 0.0f;
#pragma unroll
    for (int k = 0; k < 16; ++k) acc = fmaf(wgt_[k], p[off[k]], acc);
    outp[(size_t)c * (OUT_H * OUT_W)] = acc;
  }
}

extern "C" void kernel_launch(void* const* d_in, const int* in_sizes, int n_in,
                              void* d_out, int out_size, void* d_ws, size_t ws_size,
                              hipStream_t stream) {
  const float* input = (const float*)d_in[0];
  const float* rois = (const float*)d_in[1];
  float* out = (float*)d_out;
  const int R = in_sizes[1] / 17;
  const int N = in_sizes[0] / (C_DIM * HW_DIM);
  const size_t need = (size_t)in_sizes[0] * sizeof(float);
  if (ws_size >= need) {
    float* nhwc = (float*)d_ws;
    nchw_to_nhwc<<<dim3(N * 1600), dim3(256), 0, stream>>>(input, nhwc);
    bezier_gather<<<dim3(R * OUT_H), dim3(256), 0, stream>>>(nhwc, rois, out);
  } else {
    bezier_align_fallback<<<dim3(R * OUT_H), dim3(256), 0, stream>>>(input, rois, out);
  }
}

// Round 7
// 388.301 us; speedup vs baseline: 1.2923x; 1.1109x over previous
//
#include <hip/hip_runtime.h>
#include <hip/hip_fp16.h>

// BezierAlign, R9 (= R8 resubmit after infra failure): fp16 NHWC intermediate.
//  - Pass 1 transposes NCHW fp32 -> NHWC fp16 (26 MB instead of 52 MB):
//    halves compulsory HBM reads, halves every L3-thrash re-fetch, halves
//    L2-side request bytes. Gather converts to fp32 at FMA time.
//  - Gather keeps R7 structure: per-pw deduped corner list, ALL cnt loads
//    (4..16) issued before the first FMA (wave-uniform predicated groups),
//    wave-uniform SGPR-base loads (8 B/lane, 512 B/texel, coalesced).
//  - Nontemporal output stores; XCD-aware block swizzle.

#define OUT_H 16
#define OUT_W 64
#define SPATIAL_SCALE 0.25f
#define C_DIM 256
#define H_DIM 160
#define W_DIM 160
#define HW_DIM (H_DIM * W_DIM)

typedef __attribute__((ext_vector_type(4))) float fvec4;  // native clang vec

// ---------- Pass 1: NCHW fp32 -> NHWC fp16 (vectorized transpose) ----------
__global__ __launch_bounds__(256) void nchw_to_nhwc(const float* __restrict__ in,
                                                    __half* __restrict__ outb) {
  __shared__ float t[64][65];            // t[hw_local][c_local]
  const int b = blockIdx.x;
  const int n = b / 1600;                // 1600 tiles per batch: 4 (c) x 400 (hw)
  const int tile = b - n * 1600;
  const int tc = tile & 3;
  const int tp = tile >> 2;
  const int c0 = tc * 64, p0 = tp * 64;
  const float* A = in + (size_t)n * C_DIM * HW_DIM;
  __half* B = outb + (size_t)n * HW_DIM * C_DIM;
  const int q = threadIdx.x & 15;        // float4 column index
  const int row = threadIdx.x >> 4;      // 16 rows per pass
#pragma unroll
  for (int k = 0; k < 4; ++k) {
    const int c = row + 16 * k;
    const fvec4 v = __builtin_nontemporal_load(
        (const fvec4*)(A + (size_t)(c0 + c) * HW_DIM + p0 + 4 * q));
    t[4 * q + 0][c] = v[0];              // scalar scatter: 2-way conflict (free)
    t[4 * q + 1][c] = v[1];
    t[4 * q + 2][c] = v[2];
    t[4 * q + 3][c] = v[3];
  }
  __syncthreads();
#pragma unroll
  for (int k = 0; k < 4; ++k) {
    const int h = row + 16 * k;
    union { __half2 h2[2]; uint2 u; } pk;
    pk.h2[0] = __float22half2_rn(make_float2(t[h][4 * q + 0], t[h][4 * q + 1]));
    pk.h2[1] = __float22half2_rn(make_float2(t[h][4 * q + 2], t[h][4 * q + 3]));
    // byte offset = ((p0+h)*256 + c0+4q)*2, c0+4q % 4 == 0 -> 8B aligned
    *(uint2*)(B + (size_t)(p0 + h) * C_DIM + c0 + 4 * q) = pk.u;
  }
}

// -- helpers (inline fns, not macros: avoid token-substitution hazards) --
__device__ __forceinline__ uint2 ldvh(const __half* __restrict__ fb, int pos,
                                      int voff) {
  const int p = __builtin_amdgcn_readfirstlane(pos);   // wave-uniform -> SGPR
  return *(const uint2*)(fb + (size_t)p * C_DIM + voff);  // 8B/lane, coalesced
}
__device__ __forceinline__ float wgt(int wb) {
  return __int_as_float(__builtin_amdgcn_readfirstlane(wb));
}
__device__ __forceinline__ void fma4h(float4& a, float s, uint2 u) {
  union { unsigned int v; __half2 h; } p0{u.x}, p1{u.y};
  const float2 f0 = __half22float2(p0.h);
  const float2 f1 = __half22float2(p1.h);
  a.x = fmaf(s, f0.x, a.x);
  a.y = fmaf(s, f0.y, a.y);
  a.z = fmaf(s, f1.x, a.z);
  a.w = fmaf(s, f1.y, a.w);
}

// ---------- Pass 2: gather from NHWC fp16 ----------
__global__ __launch_bounds__(256) void bezier_gather(const __half* __restrict__ feat,
                                                     const float* __restrict__ rois,
                                                     float* __restrict__ out) {
  __shared__ int2 s_geo[OUT_W * 16];     // deduped {pos, weight-bits} per pw
  __shared__ int s_cnt[OUT_W];           // entries per pw (multiple of 4)
  __shared__ float s_tile[64][65];       // store-transpose tile (c_loc x pw)

  // XCD swizzle: blk%8 -> XCD; remap so each XCD owns a contiguous chunk of
  // (r,ph) work (overlapping y-bands share that XCD's 4MB L2).
  const int nblk = (int)gridDim.x;       // R*16, divisible by 8
  const int chunk = nblk >> 3;
  const int b0 = (int)blockIdx.x;
  const int wk = (b0 & 7) * chunk + (b0 >> 3);
  const int r = wk >> 4;
  const int ph = wk & 15;

  const int tid = threadIdx.x;
  const int lane = tid & 63;
  const int q = tid >> 6;                // wave id = pw quarter

  const float* roi = rois + (size_t)r * 17;
  const int n = (int)roi[0];

  if (tid < 64) {
    const int pw = tid;
    float px[8], py[8];
#pragma unroll
    for (int k = 0; k < 8; ++k) {
      px[k] = roi[1 + 2 * k] * SPATIAL_SCALE;
      py[k] = roi[2 + 2 * k] * SPATIAL_SCALE;
    }
    const float u = (float)pw * (1.0f / OUT_W);
    const float vv = (float)ph * (1.0f / OUT_H);
    const float mt = 1.0f - u;
    const float b0f = mt * mt * mt;
    const float b1f = 3.0f * u * mt * mt;
    const float b2f = 3.0f * u * u * mt;
    const float b3f = u * u * u;
    const float x0 = b0f * px[0] + b1f * px[1] + b2f * px[2] + b3f * px[3];
    const float y0 = b0f * py[0] + b1f * py[1] + b2f * py[2] + b3f * py[3];
    const float x1 = b0f * px[4] + b1f * px[5] + b2f * px[6] + b3f * px[7];
    const float y1 = b0f * py[4] + b1f * py[5] + b2f * py[6] + b3f * py[7];
    const float xc = x1 * vv + x0 * (1.0f - vv) - 0.5f;
    const float yc = y1 * vv + y0 * (1.0f - vv) - 0.5f;
    const float roi_w = fmaxf(fabsf(px[0] - px[3]), fabsf(px[4] - px[7]));
    const float roi_h = fmaxf(fabsf(py[0] - py[3]), fabsf(py[4] - py[7]));
    const float bin_h = roi_h * (1.0f / OUT_H);
    const float bin_w = roi_w * (1.0f / OUT_W);

    int posv[16];
    float wv[16];
#pragma unroll
    for (int s = 0; s < 4; ++s) {
      const int iy = s >> 1, ix = s & 1;
      float y = yc - 0.5f * bin_h + ((float)iy + 0.5f) * bin_h * 0.5f;
      float x = xc - 0.5f * bin_w + ((float)ix + 0.5f) * bin_w * 0.5f;
      const bool valid = (y > -1.0f) && (y < (float)H_DIM) &&
                         (x > -1.0f) && (x < (float)W_DIM);
      y = fmaxf(y, 0.0f);
      x = fmaxf(x, 0.0f);
      int yl = min((int)y, H_DIM - 1);
      int xl = min((int)x, W_DIM - 1);
      const int yh = min(yl + 1, H_DIM - 1);
      const int xh = min(xl + 1, W_DIM - 1);
      if (yl >= H_DIM - 1) y = (float)yl;
      if (xl >= W_DIM - 1) x = (float)xl;
      const float ly = y - (float)yl;
      const float lx = x - (float)xl;
      const float hy = 1.0f - ly;
      const float hx = 1.0f - lx;
      const float vw = valid ? 0.25f : 0.0f;
      posv[4 * s + 0] = yl * W_DIM + xl;  wv[4 * s + 0] = vw * hy * hx;
      posv[4 * s + 1] = yl * W_DIM + xh;  wv[4 * s + 1] = vw * hy * lx;
      posv[4 * s + 2] = yh * W_DIM + xl;  wv[4 * s + 2] = vw * ly * hx;
      posv[4 * s + 3] = yh * W_DIM + xh;  wv[4 * s + 3] = vw * ly * lx;
    }
    // Static O(16^2) register merge of duplicate positions.
#pragma unroll
    for (int i = 0; i < 16; ++i) {
#pragma unroll
      for (int jj = i + 1; jj < 16; ++jj) {
        if (posv[i] == posv[jj]) { wv[i] += wv[jj]; wv[jj] = 0.0f; }
      }
    }
    // Compact nonzero entries; pad to multiple of 4 with zero-weight clones.
    int cnt = 0;
    int first_pos = 0;
#pragma unroll
    for (int i = 0; i < 16; ++i) {
      if (wv[i] != 0.0f) {
        if (cnt == 0) first_pos = posv[i];
        s_geo[pw * 16 + cnt] = make_int2(posv[i], __float_as_int(wv[i]));
        ++cnt;
      }
    }
    while (cnt & 3) {
      s_geo[pw * 16 + cnt] = make_int2(first_pos, 0);
      ++cnt;
    }
    s_cnt[pw] = cnt;
  }
  __syncthreads();

  const __half* fb = feat + (size_t)n * ((size_t)HW_DIM * C_DIM);
  const int voff = lane * 4;             // this thread's 4-channel base (halves)
  const int pw0 = q * 16;

  float4 acc[16];
#pragma unroll
  for (int j = 0; j < 16; ++j) acc[j] = make_float4(0.f, 0.f, 0.f, 0.f);

  const uint2 uz = make_uint2(0u, 0u);
  const int4 iz = make_int4(0, 0, 0, 0);

#pragma unroll
  for (int j = 0; j < 16; ++j) {
    const int cnt = __builtin_amdgcn_readfirstlane(s_cnt[pw0 + j]);
    const int4* gp4 = (const int4*)(s_geo + (pw0 + j) * 16);  // 2 entries/int4
    float4 a = acc[j];
    int4 e0, e1, e2 = iz, e3 = iz, e4 = iz, e5 = iz, e6 = iz, e7 = iz;
    uint2 v0, v1, v2, v3, v4 = uz, v5 = uz, v6 = uz, v7 = uz,
          v8 = uz, v9 = uz, v10 = uz, v11 = uz,
          v12 = uz, v13 = uz, v14 = uz, v15 = uz;
    // Issue ALL gathers before any FMA (wave-uniform scalar branches).
    e0 = gp4[0]; e1 = gp4[1];
    v0 = ldvh(fb, e0.x, voff); v1 = ldvh(fb, e0.z, voff);
    v2 = ldvh(fb, e1.x, voff); v3 = ldvh(fb, e1.z, voff);
    if (cnt > 4) {
      e2 = gp4[2]; e3 = gp4[3];
      v4 = ldvh(fb, e2.x, voff); v5 = ldvh(fb, e2.z, voff);
      v6 = ldvh(fb, e3.x, voff); v7 = ldvh(fb, e3.z, voff);
    }
    if (cnt > 8) {
      e4 = gp4[4]; e5 = gp4[5];
      v8 = ldvh(fb, e4.x, voff); v9 = ldvh(fb, e4.z, voff);
      v10 = ldvh(fb, e5.x, voff); v11 = ldvh(fb, e5.z, voff);
    }
    if (cnt > 12) {
      e6 = gp4[6]; e7 = gp4[7];
      v12 = ldvh(fb, e6.x, voff); v13 = ldvh(fb, e6.z, voff);
      v14 = ldvh(fb, e7.x, voff); v15 = ldvh(fb, e7.z, voff);
    }
    // Accumulate (fp32 math; convert at use).
    fma4h(a, wgt(e0.y), v0); fma4h(a, wgt(e0.w), v1);
    fma4h(a, wgt(e1.y), v2); fma4h(a, wgt(e1.w), v3);
    if (cnt > 4) {
      fma4h(a, wgt(e2.y), v4); fma4h(a, wgt(e2.w), v5);
      fma4h(a, wgt(e3.y), v6); fma4h(a, wgt(e3.w), v7);
    }
    if (cnt > 8) {
      fma4h(a, wgt(e4.y), v8); fma4h(a, wgt(e4.w), v9);
      fma4h(a, wgt(e5.y), v10); fma4h(a, wgt(e5.w), v11);
    }
    if (cnt > 12) {
      fma4h(a, wgt(e6.y), v12); fma4h(a, wgt(e6.w), v13);
      fma4h(a, wgt(e7.y), v14); fma4h(a, wgt(e7.w), v15);
    }
    acc[j] = a;
  }

  // Store: 4 rounds of 64 channels, LDS-transposed for pw-contiguous stores.
  // Nontemporal: keep the 268MB output stream out of L2/L3.
  const int cg = lane >> 4;              // which 64-ch group this thread holds
  const int clb = (lane & 15) * 4;       // c offset within that group
#pragma unroll 1
  for (int g = 0; g < 4; ++g) {
    __syncthreads();
    if (cg == g) {
#pragma unroll
      for (int j = 0; j < 16; ++j) {
        s_tile[clb + 0][pw0 + j] = acc[j].x;
        s_tile[clb + 1][pw0 + j] = acc[j].y;
        s_tile[clb + 2][pw0 + j] = acc[j].z;
        s_tile[clb + 3][pw0 + j] = acc[j].w;
      }
    }
    __syncthreads();
    float* ob = out + (((size_t)r * C_DIM + g * 64) * OUT_H + ph) * OUT_W;
#pragma unroll
    for (int kk = 0; kk < 16; ++kk) {
      const int cl = q + 4 * kk;
      __builtin_nontemporal_store(s_tile[cl][lane],
                                  ob + (size_t)cl * (OUT_H * OUT_W) + lane);
    }
  }
}

// ---------- Fallback (fp32, no workspace) if workspace too small ----------
__global__ __launch_bounds__(256) void bezier_align_fallback(
    const float* __restrict__ input, const float* __restrict__ rois,
    float* __restrict__ out) {
  const int blk = blockIdx.x;
  const int r = blk >> 4;
  const int ph = blk & 15;
  const int lane = threadIdx.x & 63;
  const int wave = threadIdx.x >> 6;
  const int pw = lane;
  const float* roi = rois + (size_t)r * 17;
  const int n = (int)roi[0];
  float px[8], py[8];
#pragma unroll
  for (int k = 0; k < 8; ++k) {
    px[k] = roi[1 + 2 * k] * SPATIAL_SCALE;
    py[k] = roi[2 + 2 * k] * SPATIAL_SCALE;
  }
  const float u = (float)pw * (1.0f / OUT_W);
  const float vv = (float)ph * (1.0f / OUT_H);
  const float mt = 1.0f - u;
  const float b0 = mt * mt * mt;
  const float b1 = 3.0f * u * mt * mt;
  const float b2 = 3.0f * u * u * mt;
  const float b3 = u * u * u;
  const float x0 = b0 * px[0] + b1 * px[1] + b2 * px[2] + b3 * px[3];
  const float y0 = b0 * py[0] + b1 * py[1] + b2 * py[2] + b3 * py[3];
  const float x1 = b0 * px[4] + b1 * px[5] + b2 * px[6] + b3 * px[7];
  const float y1 = b0 * py[4] + b1 * py[5] + b2 * py[6] + b3 * py[7];
  const float xc = x1 * vv + x0 * (1.0f - vv) - 0.5f;
  const float yc = y1 * vv + y0 * (1.0f - vv) - 0.5f;
  const float roi_w = fmaxf(fabsf(px[0] - px[3]), fabsf(px[4] - px[7]));
  const float roi_h = fmaxf(fabsf(py[0] - py[3]), fabsf(py[4] - py[7]));
  const float bin_h = roi_h * (1.0f / OUT_H);
  const float bin_w = roi_w * (1.0f / OUT_W);
  int off[16];
  float wgt_[16];
#pragma unroll
  for (int s = 0; s < 4; ++s) {
    const int iy = s >> 1, ix = s & 1;
    float y = yc - 0.5f * bin_h + ((float)iy + 0.5f) * bin_h * 0.5f;
    float x = xc - 0.5f * bin_w + ((float)ix + 0.5f) * bin_w * 0.5f;
    const bool valid = (y > -1.0f) && (y < (float)H_DIM) &&
                       (x > -1.0f) && (x < (float)W_DIM);
    y = fmaxf(y, 0.0f);
    x = fmaxf(x, 0.0f);
    int yl = min((int)y, H_DIM - 1);
    int xl = min((int)x, W_DIM - 1);
    const int yh = min(yl + 1, H_DIM - 1);
    const int xh = min(xl + 1, W_DIM - 1);
    if (yl >= H_DIM - 1) y = (float)yl;
    if (xl >= W_DIM - 1) x = (float)xl;
    const float ly = y - (float)yl;
    const float lx = x - (float)xl;
    const float hy = 1.0f - ly;
    const float hx = 1.0f - lx;
    const float vw = valid ? 0.25f : 0.0f;
    wgt_[4 * s + 0] = vw * hy * hx;  off[4 * s + 0] = yl * W_DIM + xl;
    wgt_[4 * s + 1] = vw * hy * lx;  off[4 * s + 1] = yl * W_DIM + xh;
    wgt_[4 * s + 2] = vw * ly * hx;  off[4 * s + 2] = yh * W_DIM + xl;
    wgt_[4 * s + 3] = vw * ly * lx;  off[4 * s + 3] = yh * W_DIM + xh;
  }
  const size_t HW = (size_t)HW_DIM;
  const float* base = input + (size_t)n * C_DIM * HW;
  float* outp = out + (((size_t)r * C_DIM) * OUT_H + ph) * OUT_W + pw;
  const int c0 = wave * 64;
#pragma unroll 2
  for (int cc = 0; cc < 64; ++cc) {
    const int c = c0 + cc;
    const float* p = base + (size_t)c * HW;
    float acc = 0.0f;
#pragma unroll
    for (int k = 0; k < 16; ++k) acc = fmaf(wgt_[k], p[off[k]], acc);
    outp[(size_t)c * (OUT_H * OUT_W)] = acc;
  }
}

extern "C" void kernel_launch(void* const* d_in, const int* in_sizes, int n_in,
                              void* d_out, int out_size, void* d_ws, size_t ws_size,
                              hipStream_t stream) {
  const float* input = (const float*)d_in[0];
  const float* rois = (const float*)d_in[1];
  float* out = (float*)d_out;
  const int R = in_sizes[1] / 17;
  const int N = in_sizes[0] / (C_DIM * HW_DIM);
  const size_t need = (size_t)in_sizes[0] * sizeof(__half);
  if (ws_size >= need) {
    __half* nhwc = (__half*)d_ws;
    nchw_to_nhwc<<<dim3(N * 1600), dim3(256), 0, stream>>>(input, nhwc);
    bezier_gather<<<dim3(R * OUT_H), dim3(256), 0, stream>>>(nhwc, rois, out);
  } else {
    bezier_align_fallback<<<dim3(R * OUT_H), dim3(256), 0, stream>>>(input, rois, out);
  }
}